// Round 1
// baseline (450.451 us; speedup 1.0000x reference)
//
#include <hip/hip_runtime.h>

#define NTHREADS 512
#define SCL (1.0f / 8192.0f)

// XOR swizzle: bijective within [0,8192), breaks small-stride LDS bank conflicts,
// keeps the buffer at exactly 64 KiB.
__device__ __forceinline__ int P(int i) { return i ^ ((i >> 5) & 31); }

// DIF butterfly: u' = u+v ; v' = (u-v)*w
__device__ __forceinline__ void bf_fwd(float2& u, float2& v, float2 w) {
  float dx = u.x - v.x, dy = u.y - v.y;
  u.x += v.x; u.y += v.y;
  v.x = dx * w.x - dy * w.y;
  v.y = dx * w.y + dy * w.x;
}

// DIT butterfly: t = v*w ; u' = u+t ; v' = u-t
__device__ __forceinline__ void bf_inv(float2& u, float2& v, float2 w) {
  float tx = v.x * w.x - v.y * w.y;
  float ty = v.x * w.y + v.y * w.x;
  v.x = u.x - tx; v.y = u.y - ty;
  u.x += tx; u.y += ty;
}

// Forward DIF trip covering stages h and h/2 (h = 1<<LH), natural->bitrev direction.
template<int LH>
__device__ __forceinline__ void fwd_trip(float2* cb) {
  constexpr int h  = 1 << LH;
  constexpr int h2 = h >> 1;
  const float w0 = -3.14159265358979f / (float)h;
  #pragma unroll
  for (int it = 0; it < 2048 / NTHREADS; ++it) {
    int q   = threadIdx.x + it * NTHREADS;
    int m   = q & (h2 - 1);
    int blk = q >> (LH - 1);
    int i0  = (blk << (LH + 1)) + m;
    int iA = P(i0), iB = P(i0 + h2), iC = P(i0 + h), iD = P(i0 + h + h2);
    float2 e0 = cb[iA], e1 = cb[iB], e2 = cb[iC], e3 = cb[iD];
    float sb, cv;
    __sincosf(w0 * (float)m, &sb, &cv);
    float2 B   = make_float2(cv, sb);            // W_{2h}^m
    float2 Bmi = make_float2(sb, -cv);           // B * (-i)
    float2 B2  = make_float2(cv * cv - sb * sb, 2.f * cv * sb); // B^2
    bf_fwd(e0, e2, B);    // stage h, pair (i0, i0+h)
    bf_fwd(e1, e3, Bmi);  // stage h, pair (i0+h/2, i0+3h/2)
    bf_fwd(e0, e1, B2);   // stage h/2
    bf_fwd(e2, e3, B2);   // stage h/2
    cb[iA] = e0; cb[iB] = e1; cb[iC] = e2; cb[iD] = e3;
  }
  __syncthreads();
}

// Inverse DIT trip covering stages h then 2h (h = 1<<LH), bitrev->natural direction.
template<int LH>
__device__ __forceinline__ void inv_trip(float2* cb) {
  constexpr int h = 1 << LH;
  const float w0 = 3.14159265358979f / (float)(2 * h);
  #pragma unroll
  for (int it = 0; it < 2048 / NTHREADS; ++it) {
    int q   = threadIdx.x + it * NTHREADS;
    int m   = q & (h - 1);
    int blk = q >> LH;
    int i0  = (blk << (LH + 2)) + m;
    int iA = P(i0), iB = P(i0 + h), iC = P(i0 + 2 * h), iD = P(i0 + 3 * h);
    float2 e0 = cb[iA], e1 = cb[iB], e2 = cb[iC], e3 = cb[iD];
    float sv, cv;
    __sincosf(w0 * (float)m, &sv, &cv);
    float2 C  = make_float2(cv, sv);             // W_{4h}^{-m} conj -> e^{+i pi m/(2h)}
    float2 C2 = make_float2(cv * cv - sv * sv, 2.f * cv * sv);
    float2 Ci = make_float2(-sv, cv);            // C * i
    bf_inv(e0, e1, C2);   // stage h
    bf_inv(e2, e3, C2);   // stage h
    bf_inv(e0, e2, C);    // stage 2h
    bf_inv(e1, e3, Ci);   // stage 2h
    cb[iA] = e0; cb[iB] = e1; cb[iC] = e2; cb[iD] = e3;
  }
  __syncthreads();
}

// Final forward stage h=1 (twiddle = 1), used by the filter FFT.
__device__ __forceinline__ void fwd_final(float2* cb) {
  #pragma unroll
  for (int k = 0; k < 8; ++k) {
    int p = threadIdx.x + NTHREADS * k;
    int iA = P(2 * p), iB = P(2 * p + 1);
    float2 u = cb[iA], v = cb[iB];
    cb[iA] = make_float2(u.x + v.x, u.y + v.y);
    cb[iB] = make_float2(u.x - v.x, u.y - v.y);
  }
  __syncthreads();
}

// Fused: forward h=1 stage + pointwise multiply by T-hat (pre-scaled 1/L) + inverse h=1 stage.
__device__ __forceinline__ void fused_mid(float2* cb, const float2* Tr) {
  #pragma unroll
  for (int k = 0; k < 8; ++k) {
    int p = threadIdx.x + NTHREADS * k;
    int iA = P(2 * p), iB = P(2 * p + 1);
    float2 u = cb[iA], v = cb[iB];
    float2 s0 = make_float2(u.x + v.x, u.y + v.y);
    float2 s1 = make_float2(u.x - v.x, u.y - v.y);
    float2 T0 = Tr[2 * k], T1 = Tr[2 * k + 1];
    float2 a = make_float2(s0.x * T0.x - s0.y * T0.y, s0.x * T0.y + s0.y * T0.x);
    float2 b = make_float2(s1.x * T1.x - s1.y * T1.y, s1.x * T1.y + s1.y * T1.x);
    cb[iA] = make_float2(a.x + b.x, a.y + b.y);
    cb[iB] = make_float2(a.x - b.x, a.y - b.y);
  }
  __syncthreads();
}

__device__ __forceinline__ void fft_fwd12(float2* cb) {
  fwd_trip<12>(cb); fwd_trip<10>(cb); fwd_trip<8>(cb);
  fwd_trip<6>(cb);  fwd_trip<4>(cb);  fwd_trip<2>(cb);
}

__device__ __forceinline__ void fft_inv12(float2* cb) {
  inv_trip<1>(cb); inv_trip<3>(cb); inv_trip<5>(cb);
  inv_trip<7>(cb); inv_trip<9>(cb); inv_trip<11>(cb);
}

// One workgroup per channel d. xT layout: (b, d, n) contiguous rows of 4096.
// tT layout: (d, n). Output y0..y3 written IN PLACE over the consumed xT rows.
__global__ __launch_bounds__(NTHREADS)
void fftconv(float* __restrict__ xT, const float* __restrict__ tT) {
  __shared__ float2 cb[8192];   // exactly 64 KiB -> 2 workgroups/CU
  const int d = blockIdx.x;
  const int tid = threadIdx.x;

  // ---- T-hat = DIF-FFT(t_d) (bitrev order) ----
  {
    const float* tp = tT + (size_t)d * 4096;
    for (int n = tid; n < 4096; n += NTHREADS) cb[P(n)] = make_float2(tp[n], 0.f);
    for (int n = 4096 + tid; n < 8192; n += NTHREADS) cb[P(n)] = make_float2(0.f, 0.f);
    __syncthreads();
  }
  fft_fwd12(cb);
  fwd_final(cb);

  // keep T-hat in registers at exactly the positions this thread uses in fused_mid
  float2 Tr[16];
  #pragma unroll
  for (int k = 0; k < 8; ++k) {
    int p = tid + NTHREADS * k;
    float2 a = cb[P(2 * p)];
    float2 b = cb[P(2 * p + 1)];
    Tr[2 * k]     = make_float2(a.x * SCL, a.y * SCL);
    Tr[2 * k + 1] = make_float2(b.x * SCL, b.y * SCL);
  }
  __syncthreads();

  // ---- two passes: (x0 + i x1), (x2 + i x3); real filter => y0 + i y1 directly ----
  #pragma unroll 1
  for (int pass = 0; pass < 2; ++pass) {
    float* r0 = xT + ((size_t)(2 * pass)     * 1024 + d) * 4096;
    float* r1 = xT + ((size_t)(2 * pass + 1) * 1024 + d) * 4096;
    for (int n = tid; n < 4096; n += NTHREADS) cb[P(n)] = make_float2(r0[n], r1[n]);
    for (int n = 4096 + tid; n < 8192; n += NTHREADS) cb[P(n)] = make_float2(0.f, 0.f);
    __syncthreads();

    fft_fwd12(cb);
    fused_mid(cb, Tr);
    fft_inv12(cb);

    for (int n = tid; n < 4096; n += NTHREADS) {   // y = first 4096, natural order
      float2 v = cb[P(n)];
      r0[n] = v.x;
      r1[n] = v.y;
    }
    __syncthreads();
  }
}

// 64x64 tile transpose, 256 threads, float4 global I/O, padded LDS (stride 65).
// src: (R, C) -> dst: (C, R); blockIdx.z selects a slab of R*C elements.
__global__ __launch_bounds__(256)
void transpose64(const float* __restrict__ src, float* __restrict__ dst, int R, int C) {
  __shared__ float tile[64][65];
  int t  = threadIdx.x;
  int c4 = t & 15;     // float4 index within 64-wide tile
  int r  = t >> 4;     // 0..15
  size_t slab = (size_t)blockIdx.z * (size_t)R * (size_t)C;
  const float* s = src + slab;
  float* dd = dst + slab;
  int col0 = blockIdx.x * 64, row0 = blockIdx.y * 64;
  #pragma unroll
  for (int k = 0; k < 4; ++k) {
    int rr = r + 16 * k;
    const float4 v = *(const float4*)(s + (size_t)(row0 + rr) * C + col0 + 4 * c4);
    tile[rr][4 * c4 + 0] = v.x;
    tile[rr][4 * c4 + 1] = v.y;
    tile[rr][4 * c4 + 2] = v.z;
    tile[rr][4 * c4 + 3] = v.w;
  }
  __syncthreads();
  #pragma unroll
  for (int k = 0; k < 4; ++k) {
    int cc = r + 16 * k;   // output row = col0 + cc
    float4 w;
    w.x = tile[4 * c4 + 0][cc];
    w.y = tile[4 * c4 + 1][cc];
    w.z = tile[4 * c4 + 2][cc];
    w.w = tile[4 * c4 + 3][cc];
    *(float4*)(dd + (size_t)(col0 + cc) * R + row0 + 4 * c4) = w;
  }
}

extern "C" void kernel_launch(void* const* d_in, const int* in_sizes, int n_in,
                              void* d_out, int out_size, void* d_ws, size_t ws_size,
                              hipStream_t stream) {
  const float* x = (const float*)d_in[0];   // (4, 4096, 1024)
  const float* t = (const float*)d_in[1];   // (4096, 1024)
  float* out = (float*)d_out;               // (4, 4096, 1024)
  float* ws  = (float*)d_ws;
  float* xT  = ws;                                   // (4, 1024, 4096)  64 MB
  float* tT  = ws + (size_t)4 * 1024 * 4096;         // (1024, 4096)     16 MB

  // K1: transpose x and t into channel-major layout
  transpose64<<<dim3(16, 64, 4), 256, 0, stream>>>(x, xT, 4096, 1024);
  transpose64<<<dim3(16, 64, 1), 256, 0, stream>>>(t, tT, 4096, 1024);

  // K2: per-channel FFT convolution; writes y (channel-major) in place over xT
  fftconv<<<dim3(1024), NTHREADS, 0, stream>>>(xT, tT);

  // K3: transpose y back to (b, n, d)
  transpose64<<<dim3(64, 16, 4), 256, 0, stream>>>(xT, out, 1024, 4096);
}

// Round 2
// 449.397 us; speedup vs baseline: 1.0023x; 1.0023x over previous
//
#include <hip/hip_runtime.h>

#define NTHREADS 512
#define SCL (1.0f / 8192.0f)

// XOR swizzle: bijective within [0,8192), breaks small-stride LDS bank conflicts,
// keeps the buffer at exactly 64 KiB.
__device__ __forceinline__ int P(int i) { return i ^ ((i >> 5) & 31); }

// DIF butterfly: u' = u+v ; v' = (u-v)*w
__device__ __forceinline__ void bf_fwd(float2& u, float2& v, float2 w) {
  float dx = u.x - v.x, dy = u.y - v.y;
  u.x += v.x; u.y += v.y;
  v.x = dx * w.x - dy * w.y;
  v.y = dx * w.y + dy * w.x;
}

// DIT butterfly: t = v*w ; u' = u+t ; v' = u-t
__device__ __forceinline__ void bf_inv(float2& u, float2& v, float2 w) {
  float tx = v.x * w.x - v.y * w.y;
  float ty = v.x * w.y + v.y * w.x;
  v.x = u.x - tx; v.y = u.y - ty;
  u.x += tx; u.y += ty;
}

// Forward DIF trip covering stages h and h/2 (h = 1<<LH), natural->bitrev direction.
template<int LH>
__device__ __forceinline__ void fwd_trip(float2* cb) {
  constexpr int h  = 1 << LH;
  constexpr int h2 = h >> 1;
  const float w0 = -3.14159265358979f / (float)h;
  #pragma unroll
  for (int it = 0; it < 2048 / NTHREADS; ++it) {
    int q   = threadIdx.x + it * NTHREADS;
    int m   = q & (h2 - 1);
    int blk = q >> (LH - 1);
    int i0  = (blk << (LH + 1)) + m;
    int iA = P(i0), iB = P(i0 + h2), iC = P(i0 + h), iD = P(i0 + h + h2);
    float2 e0 = cb[iA], e1 = cb[iB], e2 = cb[iC], e3 = cb[iD];
    float sb, cv;
    __sincosf(w0 * (float)m, &sb, &cv);
    float2 B   = make_float2(cv, sb);            // W_{2h}^m
    float2 Bmi = make_float2(sb, -cv);           // B * (-i)
    float2 B2  = make_float2(cv * cv - sb * sb, 2.f * cv * sb); // B^2
    bf_fwd(e0, e2, B);    // stage h, pair (i0, i0+h)
    bf_fwd(e1, e3, Bmi);  // stage h, pair (i0+h/2, i0+3h/2)
    bf_fwd(e0, e1, B2);   // stage h/2
    bf_fwd(e2, e3, B2);   // stage h/2
    cb[iA] = e0; cb[iB] = e1; cb[iC] = e2; cb[iD] = e3;
  }
  __syncthreads();
}

// Inverse DIT trip covering stages h then 2h (h = 1<<LH), bitrev->natural direction.
template<int LH>
__device__ __forceinline__ void inv_trip(float2* cb) {
  constexpr int h = 1 << LH;
  const float w0 = 3.14159265358979f / (float)(2 * h);
  #pragma unroll
  for (int it = 0; it < 2048 / NTHREADS; ++it) {
    int q   = threadIdx.x + it * NTHREADS;
    int m   = q & (h - 1);
    int blk = q >> LH;
    int i0  = (blk << (LH + 2)) + m;
    int iA = P(i0), iB = P(i0 + h), iC = P(i0 + 2 * h), iD = P(i0 + 3 * h);
    float2 e0 = cb[iA], e1 = cb[iB], e2 = cb[iC], e3 = cb[iD];
    float sv, cv;
    __sincosf(w0 * (float)m, &sv, &cv);
    float2 C  = make_float2(cv, sv);             // W_{4h}^{-m} conj -> e^{+i pi m/(2h)}
    float2 C2 = make_float2(cv * cv - sv * sv, 2.f * cv * sv);
    float2 Ci = make_float2(-sv, cv);            // C * i
    bf_inv(e0, e1, C2);   // stage h
    bf_inv(e2, e3, C2);   // stage h
    bf_inv(e0, e2, C);    // stage 2h
    bf_inv(e1, e3, Ci);   // stage 2h
    cb[iA] = e0; cb[iB] = e1; cb[iC] = e2; cb[iD] = e3;
  }
  __syncthreads();
}

// Final forward stage h=1 (twiddle = 1), used by the filter FFT.
__device__ __forceinline__ void fwd_final(float2* cb) {
  #pragma unroll
  for (int k = 0; k < 8; ++k) {
    int p = threadIdx.x + NTHREADS * k;
    int iA = P(2 * p), iB = P(2 * p + 1);
    float2 u = cb[iA], v = cb[iB];
    cb[iA] = make_float2(u.x + v.x, u.y + v.y);
    cb[iB] = make_float2(u.x - v.x, u.y - v.y);
  }
  __syncthreads();
}

// Fused: forward h=1 stage + pointwise multiply by T-hat (pre-scaled 1/L) + inverse h=1 stage.
__device__ __forceinline__ void fused_mid(float2* cb, const float2* Tr) {
  #pragma unroll
  for (int k = 0; k < 8; ++k) {
    int p = threadIdx.x + NTHREADS * k;
    int iA = P(2 * p), iB = P(2 * p + 1);
    float2 u = cb[iA], v = cb[iB];
    float2 s0 = make_float2(u.x + v.x, u.y + v.y);
    float2 s1 = make_float2(u.x - v.x, u.y - v.y);
    float2 T0 = Tr[2 * k], T1 = Tr[2 * k + 1];
    float2 a = make_float2(s0.x * T0.x - s0.y * T0.y, s0.x * T0.y + s0.y * T0.x);
    float2 b = make_float2(s1.x * T1.x - s1.y * T1.y, s1.x * T1.y + s1.y * T1.x);
    cb[iA] = make_float2(a.x + b.x, a.y + b.y);
    cb[iB] = make_float2(a.x - b.x, a.y - b.y);
  }
  __syncthreads();
}

__device__ __forceinline__ void fft_fwd12(float2* cb) {
  fwd_trip<12>(cb); fwd_trip<10>(cb); fwd_trip<8>(cb);
  fwd_trip<6>(cb);  fwd_trip<4>(cb);  fwd_trip<2>(cb);
}

__device__ __forceinline__ void fft_inv12(float2* cb) {
  inv_trip<1>(cb); inv_trip<3>(cb); inv_trip<5>(cb);
  inv_trip<7>(cb); inv_trip<9>(cb); inv_trip<11>(cb);
}

// One workgroup per channel d. xT layout: (b, d, n) contiguous rows of 4096.
// tT layout: (d, n). Output y0..y3 written IN PLACE over the consumed xT rows.
// __launch_bounds__(512, 1): min 1 wave/EU -> VGPR cap 512. R1 showed 128-VGPR
// cap caused ~1 GB of spill traffic (FETCH+WRITE 8x algorithmic).
__global__ __launch_bounds__(NTHREADS, 1)
void fftconv(float* __restrict__ xT, const float* __restrict__ tT) {
  __shared__ float2 cb[8192];   // exactly 64 KiB
  const int d = blockIdx.x;
  const int tid = threadIdx.x;

  // ---- T-hat = DIF-FFT(t_d) (bitrev order) ----
  {
    const float* tp = tT + (size_t)d * 4096;
    for (int n = tid; n < 4096; n += NTHREADS) cb[P(n)] = make_float2(tp[n], 0.f);
    for (int n = 4096 + tid; n < 8192; n += NTHREADS) cb[P(n)] = make_float2(0.f, 0.f);
    __syncthreads();
  }
  fft_fwd12(cb);
  fwd_final(cb);

  // keep T-hat in registers at exactly the positions this thread uses in fused_mid
  float2 Tr[16];
  #pragma unroll
  for (int k = 0; k < 8; ++k) {
    int p = tid + NTHREADS * k;
    float2 a = cb[P(2 * p)];
    float2 b = cb[P(2 * p + 1)];
    Tr[2 * k]     = make_float2(a.x * SCL, a.y * SCL);
    Tr[2 * k + 1] = make_float2(b.x * SCL, b.y * SCL);
  }
  __syncthreads();

  // ---- two passes: (x0 + i x1), (x2 + i x3); real filter => y0 + i y1 directly ----
  #pragma unroll 1
  for (int pass = 0; pass < 2; ++pass) {
    float* r0 = xT + ((size_t)(2 * pass)     * 1024 + d) * 4096;
    float* r1 = xT + ((size_t)(2 * pass + 1) * 1024 + d) * 4096;
    for (int n = tid; n < 4096; n += NTHREADS) cb[P(n)] = make_float2(r0[n], r1[n]);
    for (int n = 4096 + tid; n < 8192; n += NTHREADS) cb[P(n)] = make_float2(0.f, 0.f);
    __syncthreads();

    fft_fwd12(cb);
    fused_mid(cb, Tr);
    fft_inv12(cb);

    for (int n = tid; n < 4096; n += NTHREADS) {   // y = first 4096, natural order
      float2 v = cb[P(n)];
      r0[n] = v.x;
      r1[n] = v.y;
    }
    __syncthreads();
  }
}

// 64x64 tile transpose, 256 threads, float4 global I/O, padded LDS (stride 65).
// src: (R, C) -> dst: (C, R); blockIdx.z selects a slab of R*C elements.
__global__ __launch_bounds__(256)
void transpose64(const float* __restrict__ src, float* __restrict__ dst, int R, int C) {
  __shared__ float tile[64][65];
  int t  = threadIdx.x;
  int c4 = t & 15;     // float4 index within 64-wide tile
  int r  = t >> 4;     // 0..15
  size_t slab = (size_t)blockIdx.z * (size_t)R * (size_t)C;
  const float* s = src + slab;
  float* dd = dst + slab;
  int col0 = blockIdx.x * 64, row0 = blockIdx.y * 64;
  #pragma unroll
  for (int k = 0; k < 4; ++k) {
    int rr = r + 16 * k;
    const float4 v = *(const float4*)(s + (size_t)(row0 + rr) * C + col0 + 4 * c4);
    tile[rr][4 * c4 + 0] = v.x;
    tile[rr][4 * c4 + 1] = v.y;
    tile[rr][4 * c4 + 2] = v.z;
    tile[rr][4 * c4 + 3] = v.w;
  }
  __syncthreads();
  #pragma unroll
  for (int k = 0; k < 4; ++k) {
    int cc = r + 16 * k;   // output row = col0 + cc
    float4 w;
    w.x = tile[4 * c4 + 0][cc];
    w.y = tile[4 * c4 + 1][cc];
    w.z = tile[4 * c4 + 2][cc];
    w.w = tile[4 * c4 + 3][cc];
    *(float4*)(dd + (size_t)(col0 + cc) * R + row0 + 4 * c4) = w;
  }
}

extern "C" void kernel_launch(void* const* d_in, const int* in_sizes, int n_in,
                              void* d_out, int out_size, void* d_ws, size_t ws_size,
                              hipStream_t stream) {
  const float* x = (const float*)d_in[0];   // (4, 4096, 1024)
  const float* t = (const float*)d_in[1];   // (4096, 1024)
  float* out = (float*)d_out;               // (4, 4096, 1024)
  float* ws  = (float*)d_ws;
  float* xT  = ws;                                   // (4, 1024, 4096)  64 MB
  float* tT  = ws + (size_t)4 * 1024 * 4096;         // (1024, 4096)     16 MB

  // K1: transpose x and t into channel-major layout
  transpose64<<<dim3(16, 64, 4), 256, 0, stream>>>(x, xT, 4096, 1024);
  transpose64<<<dim3(16, 64, 1), 256, 0, stream>>>(t, tT, 4096, 1024);

  // K2: per-channel FFT convolution; writes y (channel-major) in place over xT
  fftconv<<<dim3(1024), NTHREADS, 0, stream>>>(xT, tT);

  // K3: transpose y back to (b, n, d)
  transpose64<<<dim3(64, 16, 4), 256, 0, stream>>>(xT, out, 1024, 4096);
}

// Round 3
// 365.266 us; speedup vs baseline: 1.2332x; 1.2303x over previous
//
#include <hip/hip_runtime.h>

#define NT 512
#define SCL (1.0f / 8192.0f)
#define PI_F 3.14159265358979323846f

// XOR swizzle: bijective involution on [0,8192); spreads the stride-16 (MID)
// and block-structured trip accesses across banks (all trips hit the 4-cycle
// b64 floor). Applied consistently at EVERY cb access.
__device__ __forceinline__ int P(int i) { return i ^ ((i >> 5) & 31); }

__device__ __forceinline__ float2 cmul(float2 a, float2 b) {
  return make_float2(a.x * b.x - a.y * b.y, a.x * b.y + a.y * b.x);
}
__device__ __forceinline__ float2 csqr(float2 a) {
  return make_float2(a.x * a.x - a.y * a.y, 2.f * a.x * a.y);
}
__device__ __forceinline__ float2 cadd(float2 a, float2 b) { return make_float2(a.x + b.x, a.y + b.y); }
__device__ __forceinline__ float2 csub(float2 a, float2 b) { return make_float2(a.x - b.x, a.y - b.y); }
__device__ __forceinline__ float2 cmuli (float2 a) { return make_float2(-a.y,  a.x); } // *(+i)
__device__ __forceinline__ float2 cmulmi(float2 a) { return make_float2( a.y, -a.x); } // *(-i)

constexpr float RT2 = 0.70710678118654752440f;
constexpr float CQ1 = 0.92387953251128675613f; // cos(pi/8)
constexpr float SQ1 = 0.38268343236508977173f; // sin(pi/8)
// C16[k] = W16^k = e^{-i pi k/8}
constexpr float C16x[8] = {1.f,  CQ1,  RT2,  SQ1, 0.f, -SQ1, -RT2, -CQ1};
constexpr float C16y[8] = {0.f, -SQ1, -RT2, -CQ1, -1.f, -CQ1, -RT2, -SQ1};
// C8[k] = W8^k = e^{-i pi k/4}
constexpr float C8x[4] = {1.f,  RT2, 0.f, -RT2};
constexpr float C8y[4] = {0.f, -RT2, -1.f, -RT2};

// In-register 16-point DIF, stages at register strides 8,4,2,1.
// Stage stride s uses twiddle b^{8/s} * W_{2s}^{j mod s}; UNIT means b == 1.
template<bool UNIT>
__device__ __forceinline__ void r16_fwd(float2* e, float2 b) {
  float2 b2, b4, b8, b4mi;
  if (!UNIT) { b2 = csqr(b); b4 = csqr(b2); b8 = csqr(b4); b4mi = cmulmi(b4); }
  // stride 8
  #pragma unroll
  for (int j = 0; j < 8; ++j) {
    float2 u = e[j], v = e[j + 8];
    float2 d = csub(u, v);
    e[j] = cadd(u, v);
    if (UNIT) e[j + 8] = (j == 0) ? d : cmul(d, make_float2(C16x[j], C16y[j]));
    else {
      float2 tw = (j == 0) ? b : cmul(b, make_float2(C16x[j], C16y[j]));
      e[j + 8] = cmul(d, tw);
    }
  }
  // stride 4
  #pragma unroll
  for (int o = 0; o < 16; o += 8) {
    #pragma unroll
    for (int j = 0; j < 4; ++j) {
      float2 u = e[o + j], v = e[o + j + 4];
      float2 d = csub(u, v);
      e[o + j] = cadd(u, v);
      if (UNIT) e[o + j + 4] = (j == 0) ? d : cmul(d, make_float2(C8x[j], C8y[j]));
      else {
        float2 tw = (j == 0) ? b2 : cmul(b2, make_float2(C8x[j], C8y[j]));
        e[o + j + 4] = cmul(d, tw);
      }
    }
  }
  // stride 2: tw = b4 * {1, -i}
  #pragma unroll
  for (int o = 0; o < 16; o += 4) {
    #pragma unroll
    for (int j = 0; j < 2; ++j) {
      float2 u = e[o + j], v = e[o + j + 2];
      float2 d = csub(u, v);
      e[o + j] = cadd(u, v);
      if (UNIT) e[o + j + 2] = (j == 0) ? d : cmulmi(d);
      else      e[o + j + 2] = cmul(d, (j == 0) ? b4 : b4mi);
    }
  }
  // stride 1: tw = b8
  #pragma unroll
  for (int o = 0; o < 16; o += 2) {
    float2 u = e[o], v = e[o + 1];
    float2 d = csub(u, v);
    e[o] = cadd(u, v);
    e[o + 1] = UNIT ? d : cmul(d, b8);
  }
}

// In-register 16-point DIT inverse, stages at register strides 1,2,4,8.
// Stage stride s uses twiddle g^{8/s} * conj(W_{2s})^{j mod s}; g = conj(beta).
template<bool UNIT>
__device__ __forceinline__ void r16_inv(float2* e, float2 g) {
  float2 g2, g4, g8, g4i;
  if (!UNIT) { g2 = csqr(g); g4 = csqr(g2); g8 = csqr(g4); g4i = cmuli(g4); }
  // stride 1: tw = g8
  #pragma unroll
  for (int o = 0; o < 16; o += 2) {
    float2 t = UNIT ? e[o + 1] : cmul(e[o + 1], g8);
    float2 u = e[o];
    e[o] = cadd(u, t); e[o + 1] = csub(u, t);
  }
  // stride 2: tw = g4 * {1, +i}
  #pragma unroll
  for (int o = 0; o < 16; o += 4) {
    #pragma unroll
    for (int j = 0; j < 2; ++j) {
      float2 v = e[o + j + 2];
      float2 t;
      if (UNIT) t = (j == 0) ? v : cmuli(v);
      else      t = cmul(v, (j == 0) ? g4 : g4i);
      float2 u = e[o + j];
      e[o + j] = cadd(u, t); e[o + j + 2] = csub(u, t);
    }
  }
  // stride 4: tw = g2 * conj(C8[j])
  #pragma unroll
  for (int o = 0; o < 16; o += 8) {
    #pragma unroll
    for (int j = 0; j < 4; ++j) {
      float2 v = e[o + j + 4];
      float2 t;
      if (UNIT) t = (j == 0) ? v : cmul(v, make_float2(C8x[j], -C8y[j]));
      else      t = cmul(v, (j == 0) ? g2 : cmul(g2, make_float2(C8x[j], -C8y[j])));
      float2 u = e[o + j];
      e[o + j] = cadd(u, t); e[o + j + 4] = csub(u, t);
    }
  }
  // stride 8: tw = g * conj(C16[j])
  #pragma unroll
  for (int j = 0; j < 8; ++j) {
    float2 v = e[j + 8];
    float2 t;
    if (UNIT) t = (j == 0) ? v : cmul(v, make_float2(C16x[j], -C16y[j]));
    else      t = cmul(v, (j == 0) ? g : cmul(g, make_float2(C16x[j], -C16y[j])));
    float2 u = e[j];
    e[j] = cadd(u, t); e[j + 8] = csub(u, t);
  }
}

__device__ __forceinline__ void trip_fwd(float2* cb, int base, int G, float2 b) {
  float2 e[16];
  #pragma unroll
  for (int j = 0; j < 16; ++j) e[j] = cb[P(base + G * j)];
  r16_fwd<false>(e, b);
  #pragma unroll
  for (int j = 0; j < 16; ++j) cb[P(base + G * j)] = e[j];
}

__device__ __forceinline__ void trip_inv(float2* cb, int base, int G, float2 g) {
  float2 e[16];
  #pragma unroll
  for (int j = 0; j < 16; ++j) e[j] = cb[P(base + G * j)];
  r16_inv<false>(e, g);
  #pragma unroll
  for (int j = 0; j < 16; ++j) cb[P(base + G * j)] = e[j];
}

// One workgroup per channel d. xT: (b, d, n) rows of 4096; tT: (d, n).
// Full 8192-pt FFT conv: fwd stage h=4096 fused into load (upper half of the
// zero-padded signal is x*W), radix-16 trips A(2048..256) B(128..16),
// MID(fwd 8..1 + That* + inv 1..8, constant twiddles), D(16..128) E(256..2048),
// inv h=4096 fused into store (only lower 4096 outputs kept).
__global__ __launch_bounds__(NT)
void fftconv(float* __restrict__ xT, const float* __restrict__ tT) {
  __shared__ float2 cb[8192];   // 64 KiB
  const int tid = threadIdx.x;
  const int d = blockIdx.x;

  const int rA = tid & 255;
  const int baseA = (tid >> 8) * 4096 + rA;   // trips A/E: G=256
  const int rB = tid & 15;
  const int baseB = (tid >> 4) * 256 + rB;    // trips B/D: G=16
  const int baseM = tid * 16;                 // MID: G=1

  float sa, ca; __sincosf(-PI_F * (float)rA / 2048.f, &sa, &ca);
  const float2 betaA  = make_float2(ca, sa);        // W_4096^rA
  const float2 gammaE = make_float2(ca, -sa);       // conj
  float sb, cbv; __sincosf(-PI_F * (float)rB / 128.f, &sb, &cbv);
  const float2 betaB  = make_float2(cbv, sb);       // W_256^rB
  const float2 gammaD = make_float2(cbv, -sb);      // conj

  const float2 ROT  = make_float2(C16x[1],  C16y[1]);  // e^{-i pi/8}
  const float2 ROTc = make_float2(C16x[1], -C16y[1]);  // e^{+i pi/8}
  float sw0, cw0; __sincosf(-PI_F * (float)tid / 4096.f, &sw0, &cw0);
  const float2 W0 = make_float2(cw0, sw0);   // e^{-i pi tid/4096}

  // ---- T-hat: load(+h=4096) -> A -> B -> final radix-16 kept in registers ----
  {
    const float* tp = tT + (size_t)d * 4096;
    float2 w = W0;
    #pragma unroll
    for (int k = 0; k < 8; ++k) {
      int n = tid + NT * k;
      float tv = tp[n];
      cb[P(n)] = make_float2(tv, 0.f);
      cb[P(n + 4096)] = make_float2(tv * w.x, tv * w.y);
      w = cmul(w, ROT);
    }
  }
  __syncthreads();
  trip_fwd(cb, baseA, 256, betaA); __syncthreads();
  trip_fwd(cb, baseB, 16, betaB);  __syncthreads();
  float2 Tr[16];
  {
    float2 e[16];
    #pragma unroll
    for (int j = 0; j < 16; ++j) e[j] = cb[P(baseM + j)];
    r16_fwd<true>(e, make_float2(1.f, 0.f));
    #pragma unroll
    for (int j = 0; j < 16; ++j) Tr[j] = make_float2(e[j].x * SCL, e[j].y * SCL);
  }
  __syncthreads();

  // ---- two complex passes: (x0 + i x1), (x2 + i x3); real filter ----
  #pragma unroll 1
  for (int pass = 0; pass < 2; ++pass) {
    float* r0 = xT + ((size_t)(2 * pass)     * 1024 + d) * 4096;
    float* r1 = xT + ((size_t)(2 * pass + 1) * 1024 + d) * 4096;
    {
      float2 w = W0;
      #pragma unroll
      for (int k = 0; k < 8; ++k) {
        int n = tid + NT * k;
        float2 v = make_float2(r0[n], r1[n]);
        cb[P(n)] = v;
        cb[P(n + 4096)] = cmul(v, w);
        w = cmul(w, ROT);
      }
    }
    __syncthreads();
    trip_fwd(cb, baseA, 256, betaA); __syncthreads();
    trip_fwd(cb, baseB, 16, betaB);  __syncthreads();
    {
      float2 e[16];
      #pragma unroll
      for (int j = 0; j < 16; ++j) e[j] = cb[P(baseM + j)];
      r16_fwd<true>(e, make_float2(1.f, 0.f));
      #pragma unroll
      for (int j = 0; j < 16; ++j) e[j] = cmul(e[j], Tr[j]);
      r16_inv<true>(e, make_float2(1.f, 0.f));
      #pragma unroll
      for (int j = 0; j < 16; ++j) cb[P(baseM + j)] = e[j];
    }
    __syncthreads();
    trip_inv(cb, baseB, 16, gammaD);  __syncthreads();
    trip_inv(cb, baseA, 256, gammaE); __syncthreads();
    {
      float2 w = make_float2(cw0, -sw0);   // e^{+i pi tid/4096}
      #pragma unroll
      for (int k = 0; k < 8; ++k) {
        int n = tid + NT * k;
        float2 u = cb[P(n)];
        float2 v = cmul(cb[P(n + 4096)], w);
        r0[n] = u.x + v.x;
        r1[n] = u.y + v.y;
        w = cmul(w, ROTc);
      }
    }
    __syncthreads();
  }
}

// 64x64 tile transpose, 256 threads, float4 global I/O, padded LDS.
__global__ __launch_bounds__(256)
void transpose64(const float* __restrict__ src, float* __restrict__ dst, int R, int C) {
  __shared__ float tile[64][65];
  int t  = threadIdx.x;
  int c4 = t & 15;
  int r  = t >> 4;
  size_t slab = (size_t)blockIdx.z * (size_t)R * (size_t)C;
  const float* s = src + slab;
  float* dd = dst + slab;
  int col0 = blockIdx.x * 64, row0 = blockIdx.y * 64;
  #pragma unroll
  for (int k = 0; k < 4; ++k) {
    int rr = r + 16 * k;
    const float4 v = *(const float4*)(s + (size_t)(row0 + rr) * C + col0 + 4 * c4);
    tile[rr][4 * c4 + 0] = v.x;
    tile[rr][4 * c4 + 1] = v.y;
    tile[rr][4 * c4 + 2] = v.z;
    tile[rr][4 * c4 + 3] = v.w;
  }
  __syncthreads();
  #pragma unroll
  for (int k = 0; k < 4; ++k) {
    int cc = r + 16 * k;
    float4 w;
    w.x = tile[4 * c4 + 0][cc];
    w.y = tile[4 * c4 + 1][cc];
    w.z = tile[4 * c4 + 2][cc];
    w.w = tile[4 * c4 + 3][cc];
    *(float4*)(dd + (size_t)(col0 + cc) * R + row0 + 4 * c4) = w;
  }
}

extern "C" void kernel_launch(void* const* d_in, const int* in_sizes, int n_in,
                              void* d_out, int out_size, void* d_ws, size_t ws_size,
                              hipStream_t stream) {
  const float* x = (const float*)d_in[0];   // (4, 4096, 1024)
  const float* t = (const float*)d_in[1];   // (4096, 1024)
  float* out = (float*)d_out;               // (4, 4096, 1024)
  float* ws  = (float*)d_ws;
  float* xT  = ws;                                   // (4, 1024, 4096)  64 MB
  float* tT  = ws + (size_t)4 * 1024 * 4096;         // (1024, 4096)     16 MB

  transpose64<<<dim3(16, 64, 4), 256, 0, stream>>>(x, xT, 4096, 1024);
  transpose64<<<dim3(16, 64, 1), 256, 0, stream>>>(t, tT, 4096, 1024);

  fftconv<<<dim3(1024), NT, 0, stream>>>(xT, tT);

  transpose64<<<dim3(64, 16, 4), 256, 0, stream>>>(xT, out, 1024, 4096);
}

// Round 4
// 227.801 us; speedup vs baseline: 1.9774x; 1.6034x over previous
//
#include <hip/hip_runtime.h>

#define NT 256
#define SCL (1.0f / 8192.0f)
#define PI_F 3.14159265358979323846f

// XOR swizzle: bijective involution on [0,8192) (XORs bits 9..5 into bits 4..0);
// spreads the power-of-2 strided trip accesses across banks. Applied at EVERY cb access.
__device__ __forceinline__ int P(int i) { return i ^ ((i >> 5) & 31); }

__device__ __forceinline__ float2 cmul(float2 a, float2 b) {
  return make_float2(a.x * b.x - a.y * b.y, a.x * b.y + a.y * b.x);
}
__device__ __forceinline__ float2 csqr(float2 a) {
  return make_float2(a.x * a.x - a.y * a.y, 2.f * a.x * a.y);
}
__device__ __forceinline__ float2 cadd(float2 a, float2 b) { return make_float2(a.x + b.x, a.y + b.y); }
__device__ __forceinline__ float2 csub(float2 a, float2 b) { return make_float2(a.x - b.x, a.y - b.y); }
__device__ __forceinline__ float2 cmuli (float2 a) { return make_float2(-a.y,  a.x); } // *(+i)
__device__ __forceinline__ float2 cmulmi(float2 a) { return make_float2( a.y, -a.x); } // *(-i)

constexpr float RT2 = 0.70710678118654752440f;
constexpr float CQ1 = 0.92387953251128675613f; // cos(pi/8)
constexpr float SQ1 = 0.38268343236508977173f; // sin(pi/8)
// C16[k] = W16^k = e^{-i pi k/8}
constexpr float C16x[8] = {1.f,  CQ1,  RT2,  SQ1, 0.f, -SQ1, -RT2, -CQ1};
constexpr float C16y[8] = {0.f, -SQ1, -RT2, -CQ1, -1.f, -CQ1, -RT2, -SQ1};
// C8[k] = W8^k = e^{-i pi k/4}
constexpr float C8x[4] = {1.f,  RT2, 0.f, -RT2};
constexpr float C8y[4] = {0.f, -RT2, -1.f, -RT2};
// load/store rotation step: e^{-i pi/16} (256-thread stride over L=8192)
constexpr float CP16 = 0.98078528040323044913f; // cos(pi/16)
constexpr float SP16 = 0.19509032201612826785f; // sin(pi/16)

// In-register 16-point DIF, stages at register strides 8,4,2,1.
// Stage stride s uses twiddle b^{8/s} * W_{2s}^{j mod s}; UNIT means b == 1.
template<bool UNIT>
__device__ __forceinline__ void r16_fwd(float2* e, float2 b) {
  float2 b2, b4, b8, b4mi;
  if (!UNIT) { b2 = csqr(b); b4 = csqr(b2); b8 = csqr(b4); b4mi = cmulmi(b4); }
  #pragma unroll
  for (int j = 0; j < 8; ++j) {
    float2 u = e[j], v = e[j + 8];
    float2 d = csub(u, v);
    e[j] = cadd(u, v);
    if (UNIT) e[j + 8] = (j == 0) ? d : cmul(d, make_float2(C16x[j], C16y[j]));
    else {
      float2 tw = (j == 0) ? b : cmul(b, make_float2(C16x[j], C16y[j]));
      e[j + 8] = cmul(d, tw);
    }
  }
  #pragma unroll
  for (int o = 0; o < 16; o += 8) {
    #pragma unroll
    for (int j = 0; j < 4; ++j) {
      float2 u = e[o + j], v = e[o + j + 4];
      float2 d = csub(u, v);
      e[o + j] = cadd(u, v);
      if (UNIT) e[o + j + 4] = (j == 0) ? d : cmul(d, make_float2(C8x[j], C8y[j]));
      else {
        float2 tw = (j == 0) ? b2 : cmul(b2, make_float2(C8x[j], C8y[j]));
        e[o + j + 4] = cmul(d, tw);
      }
    }
  }
  #pragma unroll
  for (int o = 0; o < 16; o += 4) {
    #pragma unroll
    for (int j = 0; j < 2; ++j) {
      float2 u = e[o + j], v = e[o + j + 2];
      float2 d = csub(u, v);
      e[o + j] = cadd(u, v);
      if (UNIT) e[o + j + 2] = (j == 0) ? d : cmulmi(d);
      else      e[o + j + 2] = cmul(d, (j == 0) ? b4 : b4mi);
    }
  }
  #pragma unroll
  for (int o = 0; o < 16; o += 2) {
    float2 u = e[o], v = e[o + 1];
    float2 d = csub(u, v);
    e[o] = cadd(u, v);
    e[o + 1] = UNIT ? d : cmul(d, b8);
  }
}

// In-register 16-point DIT inverse, stages at register strides 1,2,4,8.
// Stage stride s uses twiddle g^{8/s} * conj(W_{2s})^{j mod s}; g = conj(beta).
template<bool UNIT>
__device__ __forceinline__ void r16_inv(float2* e, float2 g) {
  float2 g2, g4, g8, g4i;
  if (!UNIT) { g2 = csqr(g); g4 = csqr(g2); g8 = csqr(g4); g4i = cmuli(g4); }
  #pragma unroll
  for (int o = 0; o < 16; o += 2) {
    float2 t = UNIT ? e[o + 1] : cmul(e[o + 1], g8);
    float2 u = e[o];
    e[o] = cadd(u, t); e[o + 1] = csub(u, t);
  }
  #pragma unroll
  for (int o = 0; o < 16; o += 4) {
    #pragma unroll
    for (int j = 0; j < 2; ++j) {
      float2 v = e[o + j + 2];
      float2 t;
      if (UNIT) t = (j == 0) ? v : cmuli(v);
      else      t = cmul(v, (j == 0) ? g4 : g4i);
      float2 u = e[o + j];
      e[o + j] = cadd(u, t); e[o + j + 2] = csub(u, t);
    }
  }
  #pragma unroll
  for (int o = 0; o < 16; o += 8) {
    #pragma unroll
    for (int j = 0; j < 4; ++j) {
      float2 v = e[o + j + 4];
      float2 t;
      if (UNIT) t = (j == 0) ? v : cmul(v, make_float2(C8x[j], -C8y[j]));
      else      t = cmul(v, (j == 0) ? g2 : cmul(g2, make_float2(C8x[j], -C8y[j])));
      float2 u = e[o + j];
      e[o + j] = cadd(u, t); e[o + j + 4] = csub(u, t);
    }
  }
  #pragma unroll
  for (int j = 0; j < 8; ++j) {
    float2 v = e[j + 8];
    float2 t;
    if (UNIT) t = (j == 0) ? v : cmul(v, make_float2(C16x[j], -C16y[j]));
    else      t = cmul(v, (j == 0) ? g : cmul(g, make_float2(C16x[j], -C16y[j])));
    float2 u = e[j];
    e[j] = cadd(u, t); e[j + 8] = csub(u, t);
  }
}

// Each thread handles TWO radix-16 groups per trip: base and base+4096
// (second group has the same twiddle base since beta depends only on r).
__device__ __forceinline__ void trip_fwd2(float2* cb, int base, int G, float2 b) {
  #pragma unroll 1
  for (int g = 0; g < 2; ++g) {
    int bs = base + g * 4096;
    float2 e[16];
    #pragma unroll
    for (int j = 0; j < 16; ++j) e[j] = cb[P(bs + G * j)];
    r16_fwd<false>(e, b);
    #pragma unroll
    for (int j = 0; j < 16; ++j) cb[P(bs + G * j)] = e[j];
  }
}

__device__ __forceinline__ void trip_inv2(float2* cb, int base, int G, float2 g) {
  #pragma unroll 1
  for (int gg = 0; gg < 2; ++gg) {
    int bs = base + gg * 4096;
    float2 e[16];
    #pragma unroll
    for (int j = 0; j < 16; ++j) e[j] = cb[P(bs + G * j)];
    r16_inv<false>(e, g);
    #pragma unroll
    for (int j = 0; j < 16; ++j) cb[P(bs + G * j)] = e[j];
  }
}

// One workgroup per channel d. xT: (b, d, n) rows of 4096; tT: (d, n).
// Full 8192-pt FFT conv: fwd stage h=4096 fused into the load (upper half of the
// zero-padded signal is x*W), radix-16 trips A(2048..256) B(128..16),
// MID(fwd 8..1 + That* + inv 1..8, constant twiddles), D(16..128) E(256..2048),
// inv h=4096 fused into the store (only lower 4096 outputs kept).
// NT=256: LDS(64KiB) caps at 2 blocks/CU -> 8 waves/CU = 2 waves/SIMD ->
// VGPR budget 256 (R3's NT=512 gave 4 waves/SIMD -> 128 cap -> ~1GB spill traffic).
__global__ __launch_bounds__(NT)
void fftconv(float* __restrict__ xT, const float* __restrict__ tT) {
  __shared__ float2 cb[8192];   // 64 KiB
  const int tid = threadIdx.x;
  const int d = blockIdx.x;

  const int rA = tid;                     // trips A/E: G=256, bases tid, tid+4096
  const int rB = tid & 15;
  const int baseB = (tid >> 4) * 256 + rB; // trips B/D: G=16, bases baseB, baseB+4096
  const int baseM = tid * 16;              // MID: G=1,   bases baseM, baseM+4096

  float sa, ca; __sincosf(-PI_F * (float)rA / 2048.f, &sa, &ca);
  const float2 betaA  = make_float2(ca, sa);        // W_4096^rA
  const float2 gammaE = make_float2(ca, -sa);       // conj
  float sb, cbv; __sincosf(-PI_F * (float)rB / 128.f, &sb, &cbv);
  const float2 betaB  = make_float2(cbv, sb);       // W_256^rB
  const float2 gammaD = make_float2(cbv, -sb);      // conj

  const float2 ROT  = make_float2(CP16, -SP16);  // e^{-i pi/16}
  const float2 ROTc = make_float2(CP16,  SP16);  // e^{+i pi/16}
  float sw0, cw0; __sincosf(-PI_F * (float)tid / 4096.f, &sw0, &cw0);
  const float2 W0 = make_float2(cw0, sw0);       // e^{-i pi tid/4096}

  // ---- T-hat: load(+h=4096) -> A -> B -> final radix-16 kept in registers ----
  {
    const float* tp = tT + (size_t)d * 4096;
    float2 w = W0;
    #pragma unroll
    for (int k = 0; k < 16; ++k) {
      int n = tid + NT * k;
      float tv = tp[n];
      cb[P(n)] = make_float2(tv, 0.f);
      cb[P(n + 4096)] = make_float2(tv * w.x, tv * w.y);
      w = cmul(w, ROT);
    }
  }
  __syncthreads();
  trip_fwd2(cb, rA, 256, betaA);  __syncthreads();
  trip_fwd2(cb, baseB, 16, betaB); __syncthreads();
  float2 Tr[2][16];
  #pragma unroll
  for (int g = 0; g < 2; ++g) {
    float2 e[16];
    #pragma unroll
    for (int j = 0; j < 16; ++j) e[j] = cb[P(baseM + g * 4096 + j)];
    r16_fwd<true>(e, make_float2(1.f, 0.f));
    #pragma unroll
    for (int j = 0; j < 16; ++j) Tr[g][j] = make_float2(e[j].x * SCL, e[j].y * SCL);
  }
  __syncthreads();

  // ---- two complex passes: (x0 + i x1), (x2 + i x3); real filter ----
  #pragma unroll 1
  for (int pass = 0; pass < 2; ++pass) {
    float* r0 = xT + ((size_t)(2 * pass)     * 1024 + d) * 4096;
    float* r1 = xT + ((size_t)(2 * pass + 1) * 1024 + d) * 4096;
    {
      float2 w = W0;
      #pragma unroll
      for (int k = 0; k < 16; ++k) {
        int n = tid + NT * k;
        float2 v = make_float2(r0[n], r1[n]);
        cb[P(n)] = v;
        cb[P(n + 4096)] = cmul(v, w);
        w = cmul(w, ROT);
      }
    }
    __syncthreads();
    trip_fwd2(cb, rA, 256, betaA);  __syncthreads();
    trip_fwd2(cb, baseB, 16, betaB); __syncthreads();
    #pragma unroll
    for (int g = 0; g < 2; ++g) {
      float2 e[16];
      #pragma unroll
      for (int j = 0; j < 16; ++j) e[j] = cb[P(baseM + g * 4096 + j)];
      r16_fwd<true>(e, make_float2(1.f, 0.f));
      #pragma unroll
      for (int j = 0; j < 16; ++j) e[j] = cmul(e[j], Tr[g][j]);
      r16_inv<true>(e, make_float2(1.f, 0.f));
      #pragma unroll
      for (int j = 0; j < 16; ++j) cb[P(baseM + g * 4096 + j)] = e[j];
    }
    __syncthreads();
    trip_inv2(cb, baseB, 16, gammaD); __syncthreads();
    trip_inv2(cb, rA, 256, gammaE);  __syncthreads();
    {
      float2 w = make_float2(cw0, -sw0);   // e^{+i pi tid/4096}
      #pragma unroll
      for (int k = 0; k < 16; ++k) {
        int n = tid + NT * k;
        float2 u = cb[P(n)];
        float2 v = cmul(cb[P(n + 4096)], w);
        r0[n] = u.x + v.x;
        r1[n] = u.y + v.y;
        w = cmul(w, ROTc);
      }
    }
    __syncthreads();
  }
}

// 64x64 tile transpose, 256 threads, float4 global I/O, padded LDS.
__global__ __launch_bounds__(256)
void transpose64(const float* __restrict__ src, float* __restrict__ dst, int R, int C) {
  __shared__ float tile[64][65];
  int t  = threadIdx.x;
  int c4 = t & 15;
  int r  = t >> 4;
  size_t slab = (size_t)blockIdx.z * (size_t)R * (size_t)C;
  const float* s = src + slab;
  float* dd = dst + slab;
  int col0 = blockIdx.x * 64, row0 = blockIdx.y * 64;
  #pragma unroll
  for (int k = 0; k < 4; ++k) {
    int rr = r + 16 * k;
    const float4 v = *(const float4*)(s + (size_t)(row0 + rr) * C + col0 + 4 * c4);
    tile[rr][4 * c4 + 0] = v.x;
    tile[rr][4 * c4 + 1] = v.y;
    tile[rr][4 * c4 + 2] = v.z;
    tile[rr][4 * c4 + 3] = v.w;
  }
  __syncthreads();
  #pragma unroll
  for (int k = 0; k < 4; ++k) {
    int cc = r + 16 * k;
    float4 w;
    w.x = tile[4 * c4 + 0][cc];
    w.y = tile[4 * c4 + 1][cc];
    w.z = tile[4 * c4 + 2][cc];
    w.w = tile[4 * c4 + 3][cc];
    *(float4*)(dd + (size_t)(col0 + cc) * R + row0 + 4 * c4) = w;
  }
}

extern "C" void kernel_launch(void* const* d_in, const int* in_sizes, int n_in,
                              void* d_out, int out_size, void* d_ws, size_t ws_size,
                              hipStream_t stream) {
  const float* x = (const float*)d_in[0];   // (4, 4096, 1024)
  const float* t = (const float*)d_in[1];   // (4096, 1024)
  float* out = (float*)d_out;               // (4, 4096, 1024)
  float* ws  = (float*)d_ws;
  float* xT  = ws;                                   // (4, 1024, 4096)  64 MB
  float* tT  = ws + (size_t)4 * 1024 * 4096;         // (1024, 4096)     16 MB

  transpose64<<<dim3(16, 64, 4), 256, 0, stream>>>(x, xT, 4096, 1024);
  transpose64<<<dim3(16, 64, 1), 256, 0, stream>>>(t, tT, 4096, 1024);

  fftconv<<<dim3(1024), NT, 0, stream>>>(xT, tT);

  transpose64<<<dim3(64, 16, 4), 256, 0, stream>>>(xT, out, 1024, 4096);
}